// Round 12
// baseline (694.342 us; speedup 1.0000x reference)
//
#include <hip/hip_runtime.h>
#include <hip/hip_cooperative_groups.h>
#include <math.h>

namespace cg = cooperative_groups;

#define D 128
#define BSH 7
#define BMASK 127
#define NT 128         // targets per bucket
#define NB 782         // buckets
#define CAP 4608       // per-bucket capacity (mean 4092, +8 sigma) — validated r4/r5/r6
#define EPB 2048       // edges per bin unit (8 per thread)
#define LDA 136        // LDS row stride (bf16): 2-way bank aliasing = free
#define SMEM_BYTES 20480

typedef unsigned short ushort_t;
typedef unsigned int uint_t;
typedef __attribute__((ext_vector_type(8))) short bfrag;   // 8 bf16 = 4 VGPRs
typedef __attribute__((ext_vector_type(4))) float ffrag;   // 4 fp32 acc

__device__ inline ushort_t f2bf(float f) {
    uint_t u = __float_as_uint(f);
    uint_t r = (u + 0x7FFFu + ((u >> 16) & 1u)) >> 16;
    return (ushort_t)r;
}

// ---------------- bin one chunk of EPB edges (scattered flush; 6.3 KB LDS) ----------------
__device__ void dev_bin(int v, int e, char* smem, const int* __restrict__ src,
                        const int* __restrict__ tgt, int* __restrict__ bucket_cur,
                        uint_t* __restrict__ binned, const float* __restrict__ W,
                        ushort_t* __restrict__ Wt) {
    int* lcnt = (int*)smem;
    int* lbase = lcnt + NB;
    int tid = threadIdx.x;
    __syncthreads();   // smem reuse guard vs previous unit

    if (v < 16) {      // fused Wt[n][k] = bf16(W[k][n]) in first 16 units
        int nrow = v * 8 + (tid >> 5);
        int k0 = (tid & 31) * 4;
        ushort4 o;
        o.x = f2bf(W[(size_t)(k0 + 0) * D + nrow]);
        o.y = f2bf(W[(size_t)(k0 + 1) * D + nrow]);
        o.z = f2bf(W[(size_t)(k0 + 2) * D + nrow]);
        o.w = f2bf(W[(size_t)(k0 + 3) * D + nrow]);
        *(ushort4*)&Wt[(size_t)nrow * D + k0] = o;
    }

    int base = v * EPB;
    for (int i = tid; i < NB; i += 256) lcnt[i] = 0;
    __syncthreads();

    int myb[8], myrank[8];
    uint_t myval[8];
#pragma unroll
    for (int k = 0; k < 8; ++k) {
        int i = base + k * 256 + tid;
        if (i < e) {
            int t = tgt[i];
            int s = src[i];
            myb[k] = t >> BSH;
            myval[k] = ((uint_t)s << BSH) | (uint_t)(t & BMASK);
            myrank[k] = atomicAdd(&lcnt[myb[k]], 1);
        } else {
            myb[k] = -1;
        }
    }
    __syncthreads();
    for (int i = tid; i < NB; i += 256) {
        int c = lcnt[i];
        lbase[i] = (c > 0) ? atomicAdd(&bucket_cur[i], c) : 0;
    }
    __syncthreads();
#pragma unroll
    for (int k = 0; k < 8; ++k) {
        if (myb[k] >= 0) {
            int slot = lbase[myb[k]] + myrank[k];
            if (slot < CAP) binned[(size_t)myb[k] * CAP + slot] = myval[k];
        }
    }
}

// ---------------- in-place counting sort of one bucket + rowinfo/dinv (20 KB LDS) ----------------
__device__ void dev_sort(int b, int n, char* smem, uint_t* __restrict__ binned,
                         const int* __restrict__ bucket_cur, int* __restrict__ rowinfo,
                         float* __restrict__ dinv) {
    uint_t* sout = (uint_t*)smem;               // 18432 B
    int* scnt = (int*)(smem + CAP * 4);         // 128
    int* sbeg = scnt + NT;
    int* sofs = sbeg + NT;
    int tid = threadIdx.x;
    int lane = tid & 63;
    __syncthreads();   // smem reuse guard

    int nb = min(bucket_cur[b], CAP);
    uint_t* bin = binned + (size_t)b * CAP;

    if (tid < NT) scnt[tid] = 0;
    __syncthreads();
    for (int i = tid; i < nb; i += 256)
        atomicAdd(&scnt[bin[i] & BMASK], 1);
    __syncthreads();
    if (tid < 64) {   // exclusive scan over 128 counters: two 64-halves via shfl (validated r5)
        int c0 = scnt[lane];
        int c1 = scnt[lane + 64];
        int x0 = c0, x1 = c1;
#pragma unroll
        for (int off = 1; off < 64; off <<= 1) {
            int y0 = __shfl_up(x0, off);
            int y1 = __shfl_up(x1, off);
            if (lane >= off) { x0 += y0; x1 += y1; }
        }
        int tot0 = __shfl(x0, 63);
        x1 += tot0;
        sbeg[lane] = x0 - c0;      sofs[lane] = x0 - c0;
        sbeg[lane + 64] = x1 - c1; sofs[lane + 64] = x1 - c1;
    }
    __syncthreads();
    if (tid < NT) {
        int t = (b << BSH) + tid;
        if (t < n) {
            int beg = sbeg[tid];
            rowinfo[t] = (beg << 16) | (beg + scnt[tid]);   // both < 2^13
            dinv[t] = rsqrtf((float)scnt[tid] + 1.0f);
        }
    }
    __syncthreads();
    for (int i = tid; i < nb; i += 256) {
        uint_t w = bin[i];
        int r = atomicAdd(&sofs[w & BMASK], 1);
        sout[r] = w >> BSH;
    }
    __syncthreads();
    for (int i = tid; i < nb; i += 256)
        bin[i] = sout[i];
}

// ---------------- GEMM one 64-row tile: Y = bf16(X@W) UNSCALED, xnorm fused (17.4 KB LDS) ----------------
__device__ void dev_gemm(int u, int n, char* smem, const float* __restrict__ X,
                         const ushort_t* __restrict__ Wt, ushort_t* __restrict__ Y,
                         float* __restrict__ xnorm) {
    ushort_t* As = (ushort_t*)smem;   // X tile, reused as output tile
    int tid = threadIdx.x;
    int row0 = u * 64;
    __syncthreads();   // smem reuse guard

    const float4* X4 = (const float4*)X;
#pragma unroll
    for (int i2 = 0; i2 < 8; ++i2) {
        int item = i2 * 256 + tid;
        int r = item >> 5, c4 = item & 31;
        int gr = row0 + r;
        float4 v = (gr < n) ? X4[(size_t)gr * 32 + c4] : make_float4(0.f, 0.f, 0.f, 0.f);
        ushort4 bv;
        bv.x = f2bf(v.x); bv.y = f2bf(v.y); bv.z = f2bf(v.z); bv.w = f2bf(v.w);
        *(ushort4*)&As[r * LDA + c4 * 4] = bv;
        float s = v.x * v.x + v.y * v.y + v.z * v.z + v.w * v.w;
        s += __shfl_xor(s, 1);
        s += __shfl_xor(s, 2);
        s += __shfl_xor(s, 4);
        s += __shfl_xor(s, 8);
        s += __shfl_xor(s, 16);
        if ((tid & 31) == 0 && gr < n) xnorm[gr] = sqrtf(s);
    }
    __syncthreads();

    int w = tid >> 6;
    int lane = tid & 63;
    int q = lane >> 4;
    int mi = lane & 15;

    bfrag xf[4];
#pragma unroll
    for (int kt = 0; kt < 4; ++kt)
        xf[kt] = *(const bfrag*)&As[(w * 16 + mi) * LDA + kt * 32 + q * 8];

    ffrag acc[8];
#pragma unroll
    for (int nt = 0; nt < 8; ++nt) acc[nt] = (ffrag){0.f, 0.f, 0.f, 0.f};

#pragma unroll
    for (int nt = 0; nt < 8; ++nt) {
#pragma unroll
        for (int kt = 0; kt < 4; ++kt) {
            bfrag wf = *(const bfrag*)&Wt[(size_t)(nt * 16 + mi) * D + kt * 32 + q * 8];  // L1/L2-hot (r7-validated)
            acc[nt] = __builtin_amdgcn_mfma_f32_16x16x32_bf16(wf, xf[kt], acc[nt], 0, 0, 0);
        }
    }

    __syncthreads();   // As reads done -> reuse as output tile
#pragma unroll
    for (int nt = 0; nt < 8; ++nt) {
        ushort4 o;
        o.x = f2bf(acc[nt][0]);
        o.y = f2bf(acc[nt][1]);
        o.z = f2bf(acc[nt][2]);
        o.w = f2bf(acc[nt][3]);
        *(ushort4*)&As[(w * 16 + mi) * LDA + nt * 16 + q * 4] = o;
    }
    __syncthreads();

    int row = tid >> 2, seg = tid & 3;   // coalesced copy-out: thread owns one 64-B line
    int grow = row0 + row;
    if (grow < n) {
#pragma unroll
        for (int k2 = 0; k2 < 4; ++k2) {
            uint4 vv = *(const uint4*)&As[row * LDA + seg * 32 + k2 * 8];
            *(uint4*)&Y[(size_t)grow * D + seg * 32 + k2 * 8] = vv;
        }
    }
}

// ---------------- aggregate one target (wave-wide), per-edge dinv on the scalar pipe ----------------
__device__ void dev_agg(int t, const ushort_t* __restrict__ Y, const float* __restrict__ xnorm,
                        const float* __restrict__ dinv, const int* __restrict__ rowinfo,
                        const uint_t* __restrict__ binned, float b0, float b1, float sc,
                        float* __restrict__ out) {
    int lane = threadIdx.x & 63;
    const char* Yb = (const char*)Y;
    uint_t lo4 = (uint_t)lane * 4;
    float dt = dinv[t];

    uint_t p = *(const uint_t*)(Yb + (((uint_t)t << 8) + lo4));
    float a0 = dt * __uint_as_float(p << 16);
    float a1 = dt * __uint_as_float(p & 0xFFFF0000u);

    int ri = rowinfo[t];
    int slice = (t >> BSH) * CAP;
    int beg = slice + (ri >> 16);
    int end = slice + (ri & 0xFFFF);
    for (int base = beg; base < end; base += 64) {
        int m = min(end - base, 64);
        uint_t cv = binned[base + min(lane, m - 1)];
        int k = 0;
        for (; k + 16 <= m; k += 16) {
            uint_t qv[16];
            float dv[16];
#pragma unroll
            for (int j = 0; j < 16; ++j) {
                int s = __builtin_amdgcn_readlane((int)cv, k + j);
                dv[j] = dinv[s];
                qv[j] = *(const uint_t*)(Yb + ((size_t)(uint_t)s << 8) + lo4);
            }
#pragma unroll
            for (int j = 0; j < 16; ++j) {
                a0 = fmaf(dv[j], __uint_as_float(qv[j] << 16), a0);
                a1 = fmaf(dv[j], __uint_as_float(qv[j] & 0xFFFF0000u), a1);
            }
        }
        for (; k + 4 <= m; k += 4) {
            uint_t qv[4];
            float dv[4];
#pragma unroll
            for (int j = 0; j < 4; ++j) {
                int s = __builtin_amdgcn_readlane((int)cv, k + j);
                dv[j] = dinv[s];
                qv[j] = *(const uint_t*)(Yb + ((size_t)(uint_t)s << 8) + lo4);
            }
#pragma unroll
            for (int j = 0; j < 4; ++j) {
                a0 = fmaf(dv[j], __uint_as_float(qv[j] << 16), a0);
                a1 = fmaf(dv[j], __uint_as_float(qv[j] & 0xFFFF0000u), a1);
            }
        }
        for (; k < m; ++k) {
            int s = __builtin_amdgcn_readlane((int)cv, k);
            float dvs = dinv[s];
            uint_t q = *(const uint_t*)(Yb + ((size_t)(uint_t)s << 8) + lo4);
            a0 = fmaf(dvs, __uint_as_float(q << 16), a0);
            a1 = fmaf(dvs, __uint_as_float(q & 0xFFFF0000u), a1);
        }
    }

    float m0 = fmaf(dt, a0, b0);
    float m1 = fmaf(dt, a1, b1);
    float m2 = m0 * m0 + m1 * m1;
#pragma unroll
    for (int mm = 32; mm >= 1; mm >>= 1) m2 += __shfl_xor(m2, mm);
    float denom = fmaxf(sqrtf(m2), 1e-12f);
    float fac = xnorm[t] * sc / denom;
    float g0 = m0 * fac;
    float g1 = m1 * fac;
    float2 o;
    o.x = 0.5f * g0 * (1.0f + erff(g0 * 0.70710678118654752440f));
    o.y = 0.5f * g1 * (1.0f + erff(g1 * 0.70710678118654752440f));
    *(float2*)&out[(size_t)t * D + lane * 2] = o;
}

// ---------------- cooperative mega-kernel: all 4 phases, grid.sync between ----------------
__global__ __launch_bounds__(256, 6) void k_all(const int* src, const int* tgt, int e,
                                                int* bucket_cur, uint_t* binned,
                                                const float* W, ushort_t* Wt,
                                                const float* X, ushort_t* Y, float* xnorm,
                                                float* dinv, int* rowinfo,
                                                const float* bias, const float* scale,
                                                float* out, int n, int nchunk, int ngemm) {
    cg::grid_group grid = cg::this_grid();
    __shared__ __align__(16) char smem[SMEM_BYTES];
    int nblk = gridDim.x;
    int tid = threadIdx.x;

    // P0: zero bucket cursors
    for (int i = blockIdx.x * 256 + tid; i < NB; i += nblk * 256) bucket_cur[i] = 0;
    grid.sync();

    // P1: bin all edge chunks (+Wt conversion)
    for (int v = blockIdx.x; v < nchunk; v += nblk)
        dev_bin(v, e, smem, src, tgt, bucket_cur, binned, W, Wt);
    grid.sync();

    // P2: sort (units 0..NB) || gemm (units NB..NB+ngemm)
    int ntot = NB + ngemm;
    for (int v = blockIdx.x; v < ntot; v += nblk) {
        if (v < NB) dev_sort(v, n, smem, binned, bucket_cur, rowinfo, dinv);
        else        dev_gemm(v - NB, n, smem, X, Wt, Y, xnorm);
    }
    grid.sync();

    // P3: aggregate, grid-stride wave per target
    int lane = tid & 63;
    float b0 = bias[lane * 2];
    float b1 = bias[lane * 2 + 1];
    float sc = scale[0];
    int wid = blockIdx.x * 4 + (tid >> 6);
    int nw = nblk * 4;
    for (int t = wid; t < n; t += nw)
        dev_agg(t, Y, xnorm, dinv, rowinfo, binned, b0, b1, sc, out);
}

// ---------------- fallback standalone kernels (same device functions, 4 dispatches) ----------------
__global__ __launch_bounds__(256) void k_bin_s(const int* src, const int* tgt, int e,
                                               int* bucket_cur, uint_t* binned,
                                               const float* W, ushort_t* Wt) {
    __shared__ __align__(16) char smem[8192];
    dev_bin(blockIdx.x, e, smem, src, tgt, bucket_cur, binned, W, Wt);
}

__global__ __launch_bounds__(256) void k_mid_s(uint_t* binned, const int* bucket_cur,
                                               int* rowinfo, float* dinv, const float* X,
                                               const ushort_t* Wt, ushort_t* Y,
                                               float* xnorm, int n) {
    __shared__ __align__(16) char smem[SMEM_BYTES];
    int v = blockIdx.x;
    if (v < NB) dev_sort(v, n, smem, binned, bucket_cur, rowinfo, dinv);
    else        dev_gemm(v - NB, n, smem, X, Wt, Y, xnorm);
}

__global__ __launch_bounds__(256) void k_agg_s(const ushort_t* Y, const float* xnorm,
                                               const float* dinv, const int* rowinfo,
                                               const uint_t* binned, const float* bias,
                                               const float* scale, float* out, int n) {
    int t = (blockIdx.x * 256 + threadIdx.x) >> 6;
    if (t >= n) return;
    int lane = threadIdx.x & 63;
    dev_agg(t, Y, xnorm, dinv, rowinfo, binned, bias[lane * 2], bias[lane * 2 + 1],
            scale[0], out);
}

// ---------------- launch ----------------

extern "C" void kernel_launch(void* const* d_in, const int* in_sizes, int n_in,
                              void* d_out, int out_size, void* d_ws, size_t ws_size,
                              hipStream_t stream) {
    const float* X     = (const float*)d_in[0];
    const int*   ei    = (const int*)d_in[1];
    const float* W     = (const float*)d_in[2];
    const float* bias  = (const float*)d_in[3];
    const float* scale = (const float*)d_in[4];
    float* out = (float*)d_out;

    int n = in_sizes[0] / D;     // 100000
    int e = in_sizes[1] / 2;     // 3200000
    const int* src = ei;
    const int* tgt = ei + e;

    char* ws = (char*)d_ws;
    ushort_t* Y = (ushort_t*)ws;   ws += (size_t)n * D * sizeof(ushort_t);     // 25.6 MB
    uint_t* binned = (uint_t*)ws;  ws += (size_t)NB * CAP * sizeof(uint_t);    // 14.4 MB
    float* dinv = (float*)ws;      ws += (size_t)n * sizeof(float);
    float* xnorm = (float*)ws;     ws += (size_t)n * sizeof(float);
    int* rowinfo = (int*)ws;       ws += (size_t)n * sizeof(int);
    int* bucket_cur = (int*)ws;    ws += NB * sizeof(int);
    ushort_t* Wt = (ushort_t*)ws;  /* 32 KB */  // total ~41.3 MB (r11-validated)

    int nchunk = (e + EPB - 1) / EPB;   // 1563
    int ngemm = (n + 63) / 64;          // 1563

    // occupancy-sized cooperative grid, queried once
    static int coopGrid = -2;
    if (coopGrid == -2) {
        int occ = 0;
        hipError_t oe = hipOccupancyMaxActiveBlocksPerMultiprocessor(&occ, k_all, 256, 0);
        coopGrid = (oe == hipSuccess && occ >= 1) ? ((occ < 8 ? occ : 8) * 256) : -1;
    }

    bool done = false;
    if (coopGrid > 0) {
        const int* srcp = src; const int* tgtp = tgt;
        int ev = e, nv = n, ncv = nchunk, ngv = ngemm;
        int* bcur = bucket_cur; uint_t* binp = binned;
        const float* Wp = W; ushort_t* Wtp = Wt;
        const float* Xp = X; ushort_t* Yp = Y;
        float* xnp = xnorm; float* dvp = dinv; int* rip = rowinfo;
        const float* bp = bias; const float* scp = scale; float* op = out;
        void* args[] = {&srcp, &tgtp, &ev, &bcur, &binp, &Wp, &Wtp, &Xp, &Yp,
                        &xnp, &dvp, &rip, &bp, &scp, &op, &nv, &ncv, &ngv};
        hipError_t err = hipLaunchCooperativeKernel((const void*)k_all, dim3(coopGrid),
                                                    dim3(256), args, 0, stream);
        if (err == hipSuccess) done = true;
        else coopGrid = -1;   // cooperative unsupported here: never retry
    }
    if (!done) {
        hipMemsetAsync(bucket_cur, 0, NB * sizeof(int), stream);
        k_bin_s<<<nchunk, 256, 0, stream>>>(src, tgt, e, bucket_cur, binned, W, Wt);
        k_mid_s<<<NB + ngemm, 256, 0, stream>>>(binned, bucket_cur, rowinfo, dinv, X, Wt, Y, xnorm, n);
        k_agg_s<<<(n + 3) / 4, 256, 0, stream>>>(Y, xnorm, dinv, rowinfo, binned, bias, scale, out, n);
    }
}